// Round 5
// baseline (2079.098 us; speedup 1.0000x reference)
//
#include <hip/hip_runtime.h>
#include <hip/hip_bf16.h>
#include <math.h>

// SynthesisBlock (StyleGAN2-ish) on MI355X.
// f32 baseline (validated output) + self-checking bf16-MFMA probe dispatch
// whose result is signaled via its own duration in the profile (spin tiers).
//
// ws layout (floats):
//   dbg  : 256
//   wmod0: B*9*128*64 = 589824
//   wmod1: B*9*64*64  = 294912
//   y0   : B*256*256*64 = 33554432
// total 34,439,424 floats = 137.8 MB

#define BB 8
#define SRC 128
#define OUTD 256
#define CIN0 128
#define CO 64
#define WDIM 512
#define LEAK 0.2f

#define DBG_SZ 256
#define WMOD0_SZ (BB*9*CIN0*CO)
#define WMOD1_SZ (BB*9*CO*CO)

typedef __attribute__((ext_vector_type(8))) short short8;
typedef __attribute__((ext_vector_type(4))) float f32x4;

// One block per (which, b, co): computes style s, demod scale, writes
// modulated+demodulated weights [b][tap][ci][co] (co contiguous).
__global__ __launch_bounds__(128) void k_modw(
    const float* __restrict__ w, const float* __restrict__ c0,
    const float* __restrict__ c1, const float* __restrict__ y0W,
    const float* __restrict__ y0b, const float* __restrict__ y1W,
    const float* __restrict__ y1b, float* __restrict__ wsbase) {
  int idx = blockIdx.x;
  int which = idx >> 9;       // 0: conv0, 1: conv1
  int b = (idx >> 6) & 7;
  int co = idx & 63;
  const float* cw = which ? c1 : c0;
  const float* yW = which ? y1W : y0W;
  const float* yb = which ? y1b : y0b;
  int cin = which ? CO : CIN0;
  int ne = 9 * cin;
  int t = threadIdx.x;
  __shared__ float red[128];

  // style s[b][co] = sum_k w[b,k] * yW[k,co] + yb[co]
  float p = 0.f;
  for (int k = t; k < WDIM; k += 128) p += w[b * WDIM + k] * yW[k * CO + co];
  red[t] = p;
  __syncthreads();
  for (int s = 64; s > 0; s >>= 1) {
    if (t < s) red[t] += red[t + s];
    __syncthreads();
  }
  float sv = red[0] + yb[co];
  __syncthreads();

  // sum of squares of base weights for this co
  float q = 0.f;
  for (int e = t; e < ne; e += 128) {
    float v = cw[e * CO + co];
    q += v * v;
  }
  red[t] = q;
  __syncthreads();
  for (int s = 64; s > 0; s >>= 1) {
    if (t < s) red[t] += red[t + s];
    __syncthreads();
  }
  // wp = cw*sv; d = rsqrt(sum(wp^2)+eps) = rsqrt(sv^2*sumc2+eps)
  float scale = sv * rsqrtf(sv * sv * red[0] + 1e-8f);

  float* outw = wsbase + (which ? (WMOD0_SZ + b * 9 * CO * CO) : (b * 9 * CIN0 * CO));
  for (int e = t; e < ne; e += 128) outw[e * CO + co] = cw[e * CO + co] * scale;
}

// Fused conv (+ optional on-the-fly bilinear 2x upsample of src during LDS
// staging) + noise*scale + bias + leaky-relu.
// Block: 8x16 output-pixel tile x 64 couts. 256 threads: thread = 4 px x 8 co.
template <int CIN, bool UPS>
__global__ __launch_bounds__(256) void k_conv(
    const float* __restrict__ src,     // UPS: [B,128,128,CIN] else [B,256,256,CIN]
    const float* __restrict__ wmod,    // [B,9,CIN,64]
    const float* __restrict__ noise,   // [B,256,256,1]
    const float* __restrict__ nscale,  // [B,256,256,64]
    const float* __restrict__ bias,    // [64]
    float* __restrict__ dst) {         // [B,256,256,64]
  constexpr int CB = 16;
  constexpr int TR = 8, TC = 16;
  __shared__ __align__(16) float xs[CB][10][20];  // halo tile, pad 18->20
  __shared__ __align__(16) float wsh[9][CB][CO];

  int bx = blockIdx.x;
  int ox0 = (bx & 15) * TC;
  int oy0 = ((bx >> 4) & 31) * TR;
  int b = bx >> 9;

  int t = threadIdx.x;
  int cg = t & 7;         // co-group: co = cg*8 .. cg*8+7
  int pg = t >> 3;        // 0..31
  int r = pg >> 2;        // row in tile 0..7
  int c4 = (pg & 3) * 4;  // col base 0..12

  float acc[4][8];
#pragma unroll
  for (int j = 0; j < 4; j++)
#pragma unroll
    for (int o = 0; o < 8; o++) acc[j][o] = 0.f;

  const float* wb = wmod + b * 9 * CIN * CO;

  for (int ci0 = 0; ci0 < CIN; ci0 += CB) {
    __syncthreads();
    // ---- stage x halo tile (zero for conv SAME padding outside [0,256)) ----
    {
      int cio = t & 15;
      for (int pos = t >> 4; pos < 180; pos += 16) {
        int i = pos / 18, j = pos - i * 18;
        int ty = oy0 - 1 + i, tx = ox0 - 1 + j;
        float v = 0.f;
        if (ty >= 0 && ty < OUTD && tx >= 0 && tx < OUTD) {
          if constexpr (UPS) {
            // bilinear 2x (half-pixel centers, edge-clamped):
            // even t -> taps (k-1,k) w=(.25,.75); odd t -> (k,k+1) w=(.75,.25)
            int ky = ty >> 1, kx = tx >> 1;
            int y0i = (ty & 1) ? ky : ky - 1;
            float wy0 = (ty & 1) ? 0.75f : 0.25f;
            int x0i = (tx & 1) ? kx : kx - 1;
            float wx0 = (tx & 1) ? 0.75f : 0.25f;
            int y1i = y0i + 1, x1i = x0i + 1;
            y0i = y0i < 0 ? 0 : y0i;
            x0i = x0i < 0 ? 0 : x0i;
            y1i = y1i > SRC - 1 ? SRC - 1 : y1i;
            x1i = x1i > SRC - 1 ? SRC - 1 : x1i;
            const float* sb = src + (size_t)b * SRC * SRC * CIN + ci0 + cio;
            float v00 = sb[(y0i * SRC + x0i) * CIN];
            float v01 = sb[(y0i * SRC + x1i) * CIN];
            float v10 = sb[(y1i * SRC + x0i) * CIN];
            float v11 = sb[(y1i * SRC + x1i) * CIN];
            float wy1 = 1.f - wy0, wx1 = 1.f - wx0;
            v = wy0 * (wx0 * v00 + wx1 * v01) + wy1 * (wx0 * v10 + wx1 * v11);
          } else {
            v = src[(((size_t)b * OUTD + ty) * OUTD + tx) * CIN + ci0 + cio];
          }
        }
        xs[cio][i][j] = v;
      }
    }
    // ---- stage weights [9][CB][64] ----
    for (int e = t; e < 9 * CB * (CO / 4); e += 256) {
      int coq = e & 15;
      int ci = (e >> 4) & (CB - 1);
      int tap = e >> 8;
      float4 v = *reinterpret_cast<const float4*>(wb + (tap * CIN + ci0 + ci) * CO + coq * 4);
      *reinterpret_cast<float4*>(&wsh[tap][ci][coq * 4]) = v;
    }
    __syncthreads();
    // ---- compute ----
#pragma unroll 1
    for (int ci = 0; ci < CB; ++ci) {
      float xr[3][6];
#pragma unroll
      for (int dy = 0; dy < 3; dy++)
#pragma unroll
        for (int dc = 0; dc < 6; dc++) xr[dy][dc] = xs[ci][r + dy][c4 + dc];
#pragma unroll
      for (int tap = 0; tap < 9; tap++) {
        int sy = tap / 3, sx = tap % 3;
        float wv[8];
#pragma unroll
        for (int o = 0; o < 8; o++) wv[o] = wsh[tap][ci][cg * 8 + o];
#pragma unroll
        for (int j = 0; j < 4; j++)
#pragma unroll
          for (int o = 0; o < 8; o++) acc[j][o] += xr[sy][j + sx] * wv[o];
      }
    }
  }

  // ---- epilogue: noise, bias, leaky, store ----
  int oy = oy0 + r;
  size_t obase = ((size_t)b * OUTD + oy) * OUTD + ox0 + c4;
#pragma unroll
  for (int j = 0; j < 4; j++) {
    float nz = noise[obase + j];
    size_t pix = obase + j;
    float4 s0 = *reinterpret_cast<const float4*>(&nscale[pix * CO + cg * 8]);
    float4 s1 = *reinterpret_cast<const float4*>(&nscale[pix * CO + cg * 8 + 4]);
    float nsv[8] = {s0.x, s0.y, s0.z, s0.w, s1.x, s1.y, s1.z, s1.w};
#pragma unroll
    for (int o = 0; o < 8; o++) {
      float v = acc[j][o] + nsv[o] * nz + bias[cg * 8 + o];
      acc[j][o] = v > 0.f ? v : LEAK * v;
    }
    float4* dp = reinterpret_cast<float4*>(dst + pix * CO + cg * 8);
    dp[0] = make_float4(acc[j][0], acc[j][1], acc[j][2], acc[j][3]);
    dp[1] = make_float4(acc[j][4], acc[j][5], acc[j][6], acc[j][7]);
  }
}

__device__ inline short f2bf(float f) {
  __hip_bfloat16 h = __float2bfloat16(f);
  return *reinterpret_cast<short*>(&h);
}

// ---------------------------------------------------------------------------
// MFMA layout/numerics PROBE (writes nothing but 2 debug atomics in ws).
// Recomputes conv1 via mfma_f32_16x16x32_bf16 with the GUESSED A/B mapping
//   A: row=lane&15, k=(lane>>4)*8+e   B: col=lane&15, k=(lane>>4)*8+e
// (C/D mapping col=lane&15,row=(lane>>4)*4+reg is HW-verified per m89),
// applies the same epilogue, compares vs the f32 d_out, and signals via
// its own DURATION:  max|v-ref|/(|ref|+0.5) > 0.6 anywhere -> ~3.5ms spins
// (layout bug); > 0.12 -> ~0.9ms spins (numerics); else no spin (<400us).
// Wave = 16 consecutive x-pixels of one row x 64 couts (4 accumulators).
// ---------------------------------------------------------------------------
__global__ __launch_bounds__(256) void k_exp_mfma(
    const float* __restrict__ src,     // y0 f32 [8,256,256,64]
    const float* __restrict__ wmod,    // wmod1 [8,9,64,64]
    const float* __restrict__ noise,   // [8,256,256,1]
    const float* __restrict__ nscale,  // [8,256,256,64]
    const float* __restrict__ bias,    // [64]
    const float* __restrict__ ref,     // d_out (already written by f32 conv1)
    float* __restrict__ dbg) {
  int bx = blockIdx.x;
  int gx = bx & 15;            // x tile (16 px)
  int gy = (bx >> 4) & 63;     // y tile (4 rows)
  int b = bx >> 10;
  int t = threadIdx.x;
  int lane = t & 63;
  int wv = t >> 6;
  int y = gy * 4 + wv;
  int x0 = gx * 16;

  int lr = lane & 15;          // A-row / B-col / C-col
  int kg = lane >> 4;          // k-group

  const float* sb = src + (size_t)b * OUTD * OUTD * CO;
  const float* wb = wmod + b * 9 * CO * CO;

  f32x4 acc[4];
#pragma unroll
  for (int j = 0; j < 4; j++) acc[j] = (f32x4){0.f, 0.f, 0.f, 0.f};

#pragma unroll 1
  for (int step = 0; step < 18; ++step) {      // K = 9*64, 32 per step
    int tap = step >> 1;                       // whole step within one tap
    int ci0 = (step & 1) * 32 + kg * 8;
    int dy = tap / 3 - 1, dx = tap % 3 - 1;
    short8 a;
    int ty = y + dy, tx = x0 + lr + dx;
    if (ty >= 0 && ty < OUTD && tx >= 0 && tx < OUTD) {
      const float* p = sb + ((size_t)(ty * OUTD + tx) * CO + ci0);
      float4 v0 = *reinterpret_cast<const float4*>(p);
      float4 v1 = *reinterpret_cast<const float4*>(p + 4);
      a[0] = f2bf(v0.x); a[1] = f2bf(v0.y); a[2] = f2bf(v0.z); a[3] = f2bf(v0.w);
      a[4] = f2bf(v1.x); a[5] = f2bf(v1.y); a[6] = f2bf(v1.z); a[7] = f2bf(v1.w);
    } else {
#pragma unroll
      for (int e = 0; e < 8; e++) a[e] = 0;
    }
    const float* wk = wb + (tap * CO + ci0) * CO;  // + e*CO + co
#pragma unroll
    for (int jj = 0; jj < 4; ++jj) {
      int co = jj * 16 + lr;
      short8 bf;
#pragma unroll
      for (int e = 0; e < 8; ++e) bf[e] = f2bf(wk[e * CO + co]);
      acc[jj] = __builtin_amdgcn_mfma_f32_16x16x32_bf16(a, bf, acc[jj], 0, 0, 0);
    }
  }

  // epilogue + on-device compare vs f32 reference output
  float m = 0.f;
  size_t rowbase = ((size_t)b * OUTD + y) * OUTD;
#pragma unroll
  for (int jj = 0; jj < 4; ++jj) {
    int co = jj * 16 + lr;
#pragma unroll
    for (int r2 = 0; r2 < 4; ++r2) {
      int px = x0 + kg * 4 + r2;              // C row = (lane>>4)*4 + reg
      size_t pix = rowbase + px;
      float v = acc[jj][r2] + nscale[pix * CO + co] * noise[pix] + bias[co];
      v = v > 0.f ? v : LEAK * v;
      float rf = ref[pix * CO + co];
      m = fmaxf(m, fabsf(v - rf) / (fabsf(rf) + 0.5f));
    }
  }
#pragma unroll
  for (int off = 32; off; off >>= 1) m = fmaxf(m, __shfl_xor(m, off));
  if (lane == 0) {
    atomicAdd(&dbg[1], m);                     // DCE anchor (never read back)
    long long spin = m > 0.6f ? 350000 : (m > 0.12f ? 87000 : 0);  // 100MHz ticks
    if (spin) {
      atomicAdd(&dbg[0], 1.f);
      long long t0 = (long long)__builtin_amdgcn_s_memrealtime();
      while ((long long)__builtin_amdgcn_s_memrealtime() - t0 < spin)
        __builtin_amdgcn_s_sleep(8);
    }
  }
}

extern "C" void kernel_launch(void* const* d_in, const int* in_sizes, int n_in,
                              void* d_out, int out_size, void* d_ws, size_t ws_size,
                              hipStream_t stream) {
  const float* x = (const float*)d_in[0];
  const float* w = (const float*)d_in[1];
  const float* noise = (const float*)d_in[2];
  const float* conv0 = (const float*)d_in[3];
  const float* conv1 = (const float*)d_in[4];
  const float* y0W = (const float*)d_in[5];
  const float* y0b = (const float*)d_in[6];
  const float* y1W = (const float*)d_in[7];
  const float* y1b = (const float*)d_in[8];
  const float* ns0 = (const float*)d_in[9];
  const float* ns1 = (const float*)d_in[10];
  const float* bias0 = (const float*)d_in[11];
  float* out = (float*)d_out;
  float* ws = (float*)d_ws;

  float* dbg = ws;
  float* wm = ws + DBG_SZ;                 // wmod0, then wmod1
  float* y0 = wm + WMOD0_SZ + WMOD1_SZ;    // f32 intermediate

  // 1) styles + modulated/demodulated weights
  k_modw<<<1024, 128, 0, stream>>>(w, conv0, conv1, y0W, y0b, y1W, y1b, wm);

  // 2) upsample-fused conv0 + noise0 + bias + leaky -> y0 (in ws)
  k_conv<CIN0, true><<<BB * 32 * 16, 256, 0, stream>>>(
      x, wm, noise, ns0, bias0, y0);

  // 3) conv1 + noise1 + bias + leaky -> out  (authoritative, f32)
  k_conv<CO, false><<<BB * 32 * 16, 256, 0, stream>>>(
      y0, wm + WMOD0_SZ, noise, ns1, bias0, out);

  // 4) MFMA probe: recompute conv1 in bf16 MFMA, compare vs out, signal
  //    via dispatch duration. Writes only dbg[0..1]; d_out untouched.
  k_exp_mfma<<<16 * 64 * BB, 256, 0, stream>>>(
      y0, wm + WMOD0_SZ, noise, ns1, bias0, out, dbg);
}

// Round 9
// 899.094 us; speedup vs baseline: 2.3124x; 2.3124x over previous
//
#include <hip/hip_runtime.h>
#include <hip/hip_bf16.h>
#include <math.h>

// SynthesisBlock on MI355X — split-bf16 (bf16x3) MFMA implicit-GEMM version.
// k_modw: styles + demod + hi/lo bf16 weight planes (transposed [tap][co][ci]).
// k_mconv<CIN,UPS>: fused (upsample+)conv+noise+bias+leaky via 16x16x32 bf16
//   MFMA, 3-term split (ah*bh + al*bh + ah*bl) => ~f32 accuracy.
//   LDS tiles XOR-swizzled (T2-style) so fragment ds_read_b128 phases are
//   bank-conflict-free (unswizzled: 64B row stride => ~4x serialization).
// k_probe<TERMS>: duration-coded absmax of 1-/2-term bf16 vs 3-term output.
//
// ws layout: dbg f32[256]; y0 f32[8*256*256*64]; w0h/w0l short[8*9*128*64];
//            w1h/w1l short[8*9*64*64]   (137.8 MB total)

#define BB 8
#define SRC 128
#define OUTD 256
#define CIN0 128
#define CO 64
#define WDIM 512
#define LEAK 0.2f

#define DBG_FLOATS 256
#define Y0_ELEMS (BB * OUTD * OUTD * CO)
#define W0_ELEMS (BB * 9 * CIN0 * CO)
#define W1_ELEMS (BB * 9 * CO * CO)

typedef __attribute__((ext_vector_type(8))) short short8;
typedef __attribute__((ext_vector_type(4))) float f32x4;

__device__ inline short f2bf(float f) {
  __hip_bfloat16 h = __float2bfloat16(f);
  return *reinterpret_cast<short*>(&h);
}
__device__ inline float bf2f(short h) {
  unsigned u = ((unsigned)(unsigned short)h) << 16;
  return __uint_as_float(u);
}

// ---------------------------------------------------------------------------
// Styles + demod; writes hi/lo bf16 planes, layout [b][chunk][tap][co][ci32].
__global__ __launch_bounds__(128) void k_modw(
    const float* __restrict__ w, const float* __restrict__ c0,
    const float* __restrict__ c1, const float* __restrict__ y0W,
    const float* __restrict__ y0b, const float* __restrict__ y1W,
    const float* __restrict__ y1b, short* __restrict__ w0h,
    short* __restrict__ w0l, short* __restrict__ w1h, short* __restrict__ w1l) {
  int idx = blockIdx.x;
  int which = idx >> 9;  // 0: conv0, 1: conv1
  int b = (idx >> 6) & 7;
  int co = idx & 63;
  const float* cw = which ? c1 : c0;
  const float* yW = which ? y1W : y0W;
  const float* yb = which ? y1b : y0b;
  int cin = which ? CO : CIN0;
  int csh = which ? 6 : 7;
  int nch = which ? 2 : 4;
  int ne = 9 * cin;
  int t = threadIdx.x;
  __shared__ float red[128];

  float p = 0.f;
  for (int k = t; k < WDIM; k += 128) p += w[b * WDIM + k] * yW[k * CO + co];
  red[t] = p;
  __syncthreads();
  for (int s = 64; s > 0; s >>= 1) {
    if (t < s) red[t] += red[t + s];
    __syncthreads();
  }
  float sv = red[0] + yb[co];
  __syncthreads();

  float q = 0.f;
  for (int e = t; e < ne; e += 128) {
    float v = cw[e * CO + co];
    q += v * v;
  }
  red[t] = q;
  __syncthreads();
  for (int s = 64; s > 0; s >>= 1) {
    if (t < s) red[t] += red[t + s];
    __syncthreads();
  }
  float scale = sv * rsqrtf(sv * sv * red[0] + 1e-8f);

  short* ph = which ? w1h : w0h;
  short* pl = which ? w1l : w0l;
  for (int e = t; e < ne; e += 128) {
    float val = cw[e * CO + co] * scale;
    int tap = e >> csh;
    int ci = e & (cin - 1);
    short h = f2bf(val);
    short l = f2bf(val - bf2f(h));
    int o = ((((b * nch + (ci >> 5)) * 9 + tap) * 64 + co) * 32) + (ci & 31);
    ph[o] = h;
    pl[o] = l;
  }
}

// ---------------------------------------------------------------------------
// MFMA conv. Block: tile 4 rows x 64 px x 64 co; 4 waves (wave=row), each
// wave 4 px-groups x 4 co-groups of 16x16x32 MFMA, 3-term split.
// LDS swizzle: phys_idx = idx ^ sA(pi), sA = ((pi>>1)&3)*8 shorts (16B slots).
template <int CIN, bool UPS>
__global__ __launch_bounds__(256, 2) void k_mconv(
    const float* __restrict__ src,     // UPS: x [B,128,128,CIN]; else y0 f32
    const short* __restrict__ wh, const short* __restrict__ wl,
    const float* __restrict__ noise, const float* __restrict__ nscale,
    const float* __restrict__ bias, float* __restrict__ dst) {
  constexpr int NCH = CIN / 32;
  __shared__ __align__(16) short Ah[6][66][32];
  __shared__ __align__(16) short Al[6][66][32];
  __shared__ __align__(16) short Bh[64][32];
  __shared__ __align__(16) short Bl[64][32];
  __shared__ __align__(16) float xsrc[UPS ? 4 : 1][34][32];  // f32 source rows

  int bx = blockIdx.x;
  int gx = bx & 3, gy = (bx >> 2) & 63, b = bx >> 8;
  int x0 = gx * 64, oy0 = gy * 4;
  int t = threadIdx.x, lane = t & 63, wv = t >> 6;
  int lr = lane & 15, kg = lane >> 4;

  f32x4 acc[4][4];
#pragma unroll
  for (int g = 0; g < 4; g++)
#pragma unroll
    for (int j = 0; j < 4; j++) acc[g][j] = (f32x4){0.f, 0.f, 0.f, 0.f};

  int ky0 = (oy0 >> 1) - 1, kx0 = (x0 >> 1) - 1;

#pragma unroll 1
  for (int ch = 0; ch < NCH; ++ch) {
    __syncthreads();  // prior tap's compute done reading A (and xsrc)
    if constexpr (UPS) {
      // stage f32 source tile (edge-clamped rows/cols)
      for (int s = t; s < 4 * 34 * 8; s += 256) {
        int ry = s / (34 * 8);
        int rem = s - ry * (34 * 8);
        int rx = rem >> 3, qq = rem & 7;
        int ky = ky0 + ry;
        ky = ky < 0 ? 0 : (ky > SRC - 1 ? SRC - 1 : ky);
        int kx = kx0 + rx;
        kx = kx < 0 ? 0 : (kx > SRC - 1 ? SRC - 1 : kx);
        const float* sp =
            src + ((size_t)b * SRC * SRC + (size_t)ky * SRC + kx) * CIN + ch * 32 + qq * 4;
        *(f32x4*)&xsrc[ry][rx][qq * 4] = *(const f32x4*)sp;
      }
      __syncthreads();
    }
    // stage A halo tile (hi/lo split), zero outside [0,256)^2, swizzled
    for (int q2 = t; q2 < 6 * 66 * 8; q2 += 256) {
      int ri = q2 / (66 * 8);
      int rem = q2 - ri * (66 * 8);
      int pi = rem >> 3, qq = rem & 7;
      int ty = oy0 - 1 + ri, tx = x0 - 1 + pi;
      float v0 = 0.f, v1 = 0.f, v2 = 0.f, v3 = 0.f;
      if (ty >= 0 && ty < OUTD && tx >= 0 && tx < OUTD) {
        if constexpr (UPS) {
          int ky = ty >> 1, kx = tx >> 1;
          int y0i = (ty & 1) ? ky : ky - 1;
          float wy0 = (ty & 1) ? 0.75f : 0.25f;
          int x0i = (tx & 1) ? kx : kx - 1;
          float wx0 = (tx & 1) ? 0.75f : 0.25f;
          int y1i = y0i + 1, x1i = x0i + 1;
          y0i = y0i < 0 ? 0 : y0i;
          x0i = x0i < 0 ? 0 : x0i;
          y1i = y1i > SRC - 1 ? SRC - 1 : y1i;
          x1i = x1i > SRC - 1 ? SRC - 1 : x1i;
          int ry0 = y0i - ky0, ry1 = y1i - ky0;
          int rx0 = x0i - kx0, rx1 = x1i - kx0;
          f32x4 v00 = *(const f32x4*)&xsrc[ry0][rx0][qq * 4];
          f32x4 v01 = *(const f32x4*)&xsrc[ry0][rx1][qq * 4];
          f32x4 v10 = *(const f32x4*)&xsrc[ry1][rx0][qq * 4];
          f32x4 v11 = *(const f32x4*)&xsrc[ry1][rx1][qq * 4];
          float wy1 = 1.f - wy0, wx1 = 1.f - wx0;
          v0 = wy0 * (wx0 * v00[0] + wx1 * v01[0]) + wy1 * (wx0 * v10[0] + wx1 * v11[0]);
          v1 = wy0 * (wx0 * v00[1] + wx1 * v01[1]) + wy1 * (wx0 * v10[1] + wx1 * v11[1]);
          v2 = wy0 * (wx0 * v00[2] + wx1 * v01[2]) + wy1 * (wx0 * v10[2] + wx1 * v11[2]);
          v3 = wy0 * (wx0 * v00[3] + wx1 * v01[3]) + wy1 * (wx0 * v10[3] + wx1 * v11[3]);
        } else {
          const float* sp =
              src + ((size_t)b * OUTD * OUTD + (size_t)ty * OUTD + tx) * CO + ch * 32 + qq * 4;
          f32x4 vv = *(const f32x4*)sp;
          v0 = vv[0]; v1 = vv[1]; v2 = vv[2]; v3 = vv[3];
        }
      }
      short h0 = f2bf(v0), h1 = f2bf(v1), h2 = f2bf(v2), h3 = f2bf(v3);
      short l0 = f2bf(v0 - bf2f(h0)), l1 = f2bf(v1 - bf2f(h1));
      short l2 = f2bf(v2 - bf2f(h2)), l3 = f2bf(v3 - bf2f(h3));
      uint2 HP, LP;
      HP.x = (unsigned)(unsigned short)h0 | ((unsigned)(unsigned short)h1 << 16);
      HP.y = (unsigned)(unsigned short)h2 | ((unsigned)(unsigned short)h3 << 16);
      LP.x = (unsigned)(unsigned short)l0 | ((unsigned)(unsigned short)l1 << 16);
      LP.y = (unsigned)(unsigned short)l2 | ((unsigned)(unsigned short)l3 << 16);
      int ii = (qq * 4) ^ (((pi >> 1) & 3) * 8);  // swizzled short index
      *(uint2*)&Ah[ri][pi][ii] = HP;
      *(uint2*)&Al[ri][pi][ii] = LP;
    }
#pragma unroll 1
    for (int tap = 0; tap < 9; ++tap) {
      __syncthreads();  // A visible (first tap); prior compute done with B
      {
        int co = t >> 2, qq = t & 3;
        size_t base = ((((size_t)b * NCH + ch) * 9 + tap) * 64 + co) * 32 + qq * 8;
        short8 vh = *(const short8*)&wh[base];
        short8 vl = *(const short8*)&wl[base];
        int ii = (qq * 8) ^ (((co >> 1) & 3) * 8);  // swizzled short index
        *(short8*)&Bh[co][ii] = vh;
        *(short8*)&Bl[co][ii] = vl;
      }
      __syncthreads();  // B visible
      int dy = tap / 3, dx = tap % 3;
      int ri = wv + dy;
      short8 a_h[4], a_l[4], b_h[4], b_l[4];
#pragma unroll
      for (int g = 0; g < 4; g++) {
        int pi = g * 16 + lr + dx;
        int ii = (kg * 8) ^ (((pi >> 1) & 3) * 8);
        a_h[g] = *(const short8*)&Ah[ri][pi][ii];
        a_l[g] = *(const short8*)&Al[ri][pi][ii];
      }
#pragma unroll
      for (int j = 0; j < 4; j++) {
        int co = j * 16 + lr;
        int ii = (kg * 8) ^ (((co >> 1) & 3) * 8);
        b_h[j] = *(const short8*)&Bh[co][ii];
        b_l[j] = *(const short8*)&Bl[co][ii];
      }
#pragma unroll
      for (int g = 0; g < 4; g++)
#pragma unroll
        for (int j = 0; j < 4; j++) {
          acc[g][j] = __builtin_amdgcn_mfma_f32_16x16x32_bf16(a_h[g], b_h[j], acc[g][j], 0, 0, 0);
          acc[g][j] = __builtin_amdgcn_mfma_f32_16x16x32_bf16(a_l[g], b_h[j], acc[g][j], 0, 0, 0);
          acc[g][j] = __builtin_amdgcn_mfma_f32_16x16x32_bf16(a_h[g], b_l[j], acc[g][j], 0, 0, 0);
        }
    }
  }

  // epilogue: noise + bias + leaky, f32 store
  int y = oy0 + wv;
  size_t rowb = ((size_t)b * OUTD + y) * OUTD;
#pragma unroll
  for (int g = 0; g < 4; g++) {
#pragma unroll
    for (int r2 = 0; r2 < 4; r2++) {
      int px = x0 + g * 16 + kg * 4 + r2;
      size_t pix = rowb + px;
      float nz = noise[pix];
#pragma unroll
      for (int j = 0; j < 4; j++) {
        int co = j * 16 + lr;
        float v = acc[g][j][r2] + nscale[pix * CO + co] * nz + bias[co];
        dst[pix * CO + co] = v > 0.f ? v : LEAK * v;
      }
    }
  }
}

// ---------------------------------------------------------------------------
// Duration-coded probe: recompute conv1 (b=0, rows 0..63) with TERMS(1|2)
// bf16 terms, absmax vs 3-term d_out. Tier spins: m>thr0*{1,2,4,8,16} ->
// {50,100,200,400,800}us (RTC ~100MHz). Writes only dbg (DCE anchor).
template <int TERMS>
__global__ __launch_bounds__(256) void k_probe(
    const float* __restrict__ y0, const short* __restrict__ w1h,
    const short* __restrict__ w1l, const float* __restrict__ noise,
    const float* __restrict__ ns1, const float* __restrict__ bias,
    const float* __restrict__ ref, float* __restrict__ dbg, float thr0) {
  int bx = blockIdx.x;
  int gx = bx & 15, gy = bx >> 4;  // 256 blocks
  int t = threadIdx.x, lane = t & 63, wv = t >> 6;
  int y = gy * 4 + wv, x0 = gx * 16;
  int lr = lane & 15, kg = lane >> 4;

  f32x4 acc[4];
#pragma unroll
  for (int j = 0; j < 4; j++) acc[j] = (f32x4){0.f, 0.f, 0.f, 0.f};

#pragma unroll 1
  for (int step = 0; step < 18; ++step) {
    int tap = step >> 1, chh = step & 1;
    int dy = tap / 3 - 1, dx = tap % 3 - 1;
    int ty = y + dy, tx = x0 + lr + dx;
    short8 ah = {0, 0, 0, 0, 0, 0, 0, 0};
    short8 al = {0, 0, 0, 0, 0, 0, 0, 0};
    if (ty >= 0 && ty < OUTD && tx >= 0 && tx < OUTD) {
      const float* p = y0 + ((size_t)ty * OUTD + tx) * CO + chh * 32 + kg * 8;
      f32x4 u0 = *(const f32x4*)p;
      f32x4 u1 = *(const f32x4*)(p + 4);
#pragma unroll
      for (int e = 0; e < 4; e++) {
        ah[e] = f2bf(u0[e]);
        ah[4 + e] = f2bf(u1[e]);
        if constexpr (TERMS == 2) {
          al[e] = f2bf(u0[e] - bf2f(ah[e]));
          al[4 + e] = f2bf(u1[e] - bf2f(ah[4 + e]));
        }
      }
    }
#pragma unroll
    for (int j = 0; j < 4; j++) {
      int co = j * 16 + lr;
      short8 bh = *(const short8*)&w1h[((size_t)(chh * 9 + tap) * 64 + co) * 32 + kg * 8];
      acc[j] = __builtin_amdgcn_mfma_f32_16x16x32_bf16(ah, bh, acc[j], 0, 0, 0);
      if constexpr (TERMS == 2)
        acc[j] = __builtin_amdgcn_mfma_f32_16x16x32_bf16(al, bh, acc[j], 0, 0, 0);
    }
  }

  float m = 0.f;
  size_t rowb = (size_t)y * OUTD;
#pragma unroll
  for (int j = 0; j < 4; j++) {
    int co = j * 16 + lr;
#pragma unroll
    for (int r2 = 0; r2 < 4; r2++) {
      int px = x0 + kg * 4 + r2;
      size_t pix = rowb + px;
      float v = acc[j][r2] + ns1[pix * CO + co] * noise[pix] + bias[co];
      v = v > 0.f ? v : LEAK * v;
      m = fmaxf(m, fabsf(v - ref[pix * CO + co]));
    }
  }
#pragma unroll
  for (int off = 32; off; off >>= 1) m = fmaxf(m, __shfl_xor(m, off));
  if (lane == 0) {
    atomicAdd(&dbg[2 + TERMS], m);  // keep m live
    long long spin = 0;
    if (m > thr0) spin = 5000;
    if (m > 2.f * thr0) spin = 10000;
    if (m > 4.f * thr0) spin = 20000;
    if (m > 8.f * thr0) spin = 40000;
    if (m > 16.f * thr0) spin = 80000;
    if (spin) {
      long long t0 = (long long)__builtin_amdgcn_s_memrealtime();
      while ((long long)__builtin_amdgcn_s_memrealtime() - t0 < spin)
        __builtin_amdgcn_s_sleep(8);
    }
  }
}

extern "C" void kernel_launch(void* const* d_in, const int* in_sizes, int n_in,
                              void* d_out, int out_size, void* d_ws, size_t ws_size,
                              hipStream_t stream) {
  const float* x = (const float*)d_in[0];
  const float* w = (const float*)d_in[1];
  const float* noise = (const float*)d_in[2];
  const float* conv0 = (const float*)d_in[3];
  const float* conv1 = (const float*)d_in[4];
  const float* y0W = (const float*)d_in[5];
  const float* y0b = (const float*)d_in[6];
  const float* y1W = (const float*)d_in[7];
  const float* y1b = (const float*)d_in[8];
  const float* ns0 = (const float*)d_in[9];
  const float* ns1 = (const float*)d_in[10];
  const float* bias0 = (const float*)d_in[11];
  float* out = (float*)d_out;

  float* dbg = (float*)d_ws;
  float* y0 = dbg + DBG_FLOATS;
  short* w0h = (short*)(y0 + Y0_ELEMS);
  short* w0l = w0h + W0_ELEMS;
  short* w1h = w0l + W0_ELEMS;
  short* w1l = w1h + W1_ELEMS;

  k_modw<<<1024, 128, 0, stream>>>(w, conv0, conv1, y0W, y0b, y1W, y1b,
                                   w0h, w0l, w1h, w1l);

  k_mconv<CIN0, true><<<2048, 256, 0, stream>>>(x, w0h, w0l, noise, ns0, bias0, y0);

  k_mconv<CO, false><<<2048, 256, 0, stream>>>(y0, w1h, w1l, noise, ns1, bias0, out);

  // probes: 1-term and 2-term bf16 error vs 3-term output (duration-coded)
  k_probe<1><<<256, 256, 0, stream>>>(y0, w1h, w1l, noise, ns1, bias0, out, dbg, 0.004f);
  k_probe<2><<<256, 256, 0, stream>>>(y0, w1h, w1l, noise, ns1, bias0, out, dbg, 0.002f);
}